// Round 3
// baseline (6287.338 us; speedup 1.0000x reference)
//
#include <hip/hip_runtime.h>

#define BB    2      // batches
#define NN    8192   // points per batch
#define CC    64     // extra feature channels
#define NPT   1024   // npoint
#define NBLK  16     // blocks per batch
#define TPB   512    // threads per block (1 point per thread)
#define WPB   (TPB/64)       // 8 waves per block
#define WSLOTS (NBLK*WPB)    // 128 wave slots per batch

// monotonic order-preserving key for f32 (handles negatives)
__device__ __forceinline__ unsigned int fkey(float v) {
  unsigned int u = __float_as_uint(v);
  return (u & 0x80000000u) ? ~u : (u | 0x80000000u);
}

#define R64(M) \
  M(0) M(1) M(2) M(3) M(4) M(5) M(6) M(7) \
  M(8) M(9) M(10) M(11) M(12) M(13) M(14) M(15) \
  M(16) M(17) M(18) M(19) M(20) M(21) M(22) M(23) \
  M(24) M(25) M(26) M(27) M(28) M(29) M(30) M(31) \
  M(32) M(33) M(34) M(35) M(36) M(37) M(38) M(39) \
  M(40) M(41) M(42) M(43) M(44) M(45) M(46) M(47) \
  M(48) M(49) M(50) M(51) M(52) M(53) M(54) M(55) \
  M(56) M(57) M(58) M(59) M(60) M(61) M(62) M(63)

__global__ __attribute__((amdgpu_waves_per_eu(1, 2))) __launch_bounds__(TPB)
void fps_kernel(const float* __restrict__ pts,   // (B, N, 3)
                const float* __restrict__ feat,  // (B, C, N)
                int* __restrict__ out,           // (B, NPT)
                unsigned long long* __restrict__ slots) // ws: [2][B][WSLOTS]
{
  const int blk  = blockIdx.x & (NBLK - 1);
  const int b    = blockIdx.x >> 4;
  const int tid  = threadIdx.x;
  const int lane = tid & 63;
  const int w    = blk * WPB + (tid >> 6);   // wave slot within batch
  const int p    = blk * TPB + tid;          // this thread's point

  const float* Pp = pts  + (size_t)b * NN * 3 + (size_t)p * 3;
  const float* Fp = feat + (size_t)b * CC * NN + p;

  // ---- 67 named scalar SSA values (no alloca -> must live in VGPRs)
  float fx = Pp[0], fy = Pp[1], fz = Pp[2];
#define DCF(i) float fc##i = Fp[(i) * NN];
  R64(DCF)
#undef DCF
  asm volatile("" : "+v"(fx), "+v"(fy), "+v"(fz));
#define PIN(i) asm volatile("" : "+v"(fc##i));
  R64(PIN)
#undef PIN

  // ---- own norm, strictly sequential order (matches nf/dot order exactly)
  float nrm = 0.f;
  nrm += fx * fx; nrm += fy * fy; nrm += fz * fz;
#define NR(i) nrm += fc##i * fc##i;
  R64(NR)
#undef NR

  if (blk == 0 && tid == 0) out[b * NPT] = 0;

  float mind = 3.0e38f;
  int far = 0;

  for (int s = 1; s < NPT; ++s) {
    // ---- distance to `far`: uniform broadcast loads, nf computed inline
    const int fu = __builtin_amdgcn_readfirstlane(far);
    const float* Pq = pts  + (size_t)b * NN * 3 + (size_t)fu * 3;
    const float* Fq = feat + (size_t)b * CC * NN + fu;
    const float gx = Pq[0], gy = Pq[1], gz = Pq[2];
#define GL(i) const float gc##i = Fq[(i) * NN];
    R64(GL)
#undef GL
    float nf = 0.f, dot = 0.f;
    nf += gx * gx; nf += gy * gy; nf += gz * gz;
#define NF(i) nf += gc##i * gc##i;
    R64(NF)
#undef NF
    dot += fx * gx; dot += fy * gy; dot += fz * gz;
#define DT(i) dot += fc##i * gc##i;
    R64(DT)
#undef DT
    const float d = (nf + nrm) - 2.0f * dot;
    mind = fminf(mind, d);

    // ---- wave argmax (64 lanes): key = step tag | value desc | lowest idx
    unsigned long long key = ((unsigned long long)s << 45)
        | ((unsigned long long)fkey(mind) << 13)
        | (unsigned int)(8191 - p);
#pragma unroll
    for (int off = 1; off < 64; off <<= 1) {
      unsigned long long o = __shfl_xor(key, off);
      key = key > o ? key : o;
    }

    // ---- publish wave candidate; parity double-buffer prevents tag clobber
    unsigned long long* sb = slots + ((size_t)(s & 1) * BB + b) * WSLOTS;
    if (lane == 0)
      __hip_atomic_store(&sb[w], key, __ATOMIC_RELAXED, __HIP_MEMORY_SCOPE_AGENT);

    // ---- every wave polls all 128 slots (2 per lane), no syncthreads anywhere
    unsigned long long v0, v1;
    for (;;) {
      v0 = __hip_atomic_load(&sb[lane],      __ATOMIC_RELAXED, __HIP_MEMORY_SCOPE_AGENT);
      v1 = __hip_atomic_load(&sb[64 + lane], __ATOMIC_RELAXED, __HIP_MEMORY_SCOPE_AGENT);
      const bool ok = ((v0 >> 45) == (unsigned long long)s) &
                      ((v1 >> 45) == (unsigned long long)s);
      if (__all(ok)) break;
    }
    unsigned long long m = v0 > v1 ? v0 : v1;
#pragma unroll
    for (int off = 1; off < 64; off <<= 1) {
      unsigned long long o = __shfl_xor(m, off);
      m = m > o ? m : o;
    }
    far = 8191 - (int)(m & 0x1FFFu);
    if (blk == 0 && tid == 0) out[b * NPT + s] = far;
  }
}

extern "C" void kernel_launch(void* const* d_in, const int* in_sizes, int n_in,
                              void* d_out, int out_size, void* d_ws, size_t ws_size,
                              hipStream_t stream) {
  const float* pts  = (const float*)d_in[0];
  const float* feat = (const float*)d_in[1];
  int* out = (int*)d_out;
  unsigned long long* slots = (unsigned long long*)d_ws; // [2][BB][WSLOTS] = 4 KiB

  // zero the slot region every call (replay-deterministic, kills stale tags)
  hipMemsetAsync(d_ws, 0, 2 * BB * WSLOTS * sizeof(unsigned long long), stream);

  void* args[] = {(void*)&pts, (void*)&feat, (void*)&out, (void*)&slots};
  dim3 grid(BB * NBLK), block(TPB);
  hipLaunchCooperativeKernel((void*)fps_kernel, grid, block, args, 0, stream);
}

// Round 4
// 3427.872 us; speedup vs baseline: 1.8342x; 1.8342x over previous
//
#include <hip/hip_runtime.h>

#define BB    2      // batches
#define NN    8192   // points per batch
#define CC    64     // extra feature channels
#define NPT   1024   // npoint
#define NT    128    // 64-wide tiles per dim (8192/64)
#define NBLK  16     // fallback: blocks per batch
#define TPB   512    // fallback: threads per block

// monotonic order-preserving key for f32 (handles negatives)
__device__ __forceinline__ unsigned int fkey(float v) {
  unsigned int u = __float_as_uint(v);
  return (u & 0x80000000u) ? ~u : (u | 0x80000000u);
}

// ======================= two-phase path =======================

__global__ __launch_bounds__(256) void norm_kernel(
    const float* __restrict__ pts, const float* __restrict__ feat,
    float* __restrict__ norms) {
  const int g = blockIdx.x * 256 + threadIdx.x;      // 0 .. BB*NN-1
  const int b = g >> 13, i = g & (NN - 1);
  const float* P = pts + (size_t)b * NN * 3 + (size_t)i * 3;
  const float* F = feat + (size_t)b * CC * NN + i;
  float n = 0.f;
  n = fmaf(P[0], P[0], n);
  n = fmaf(P[1], P[1], n);
  n = fmaf(P[2], P[2], n);
#pragma unroll
  for (int c = 0; c < CC; ++c) { const float v = F[(size_t)c * NN]; n = fmaf(v, v, n); }
  norms[g] = n;
}

// D[b][i][j] = n_i + n_j - 2 * dot(A_i, A_j); k accumulated sequentially via fmaf
// so D[i][i] == 0 bit-exactly (same order as norm_kernel).
__global__ __launch_bounds__(256) void dist_kernel(
    const float* __restrict__ pts, const float* __restrict__ feat,
    const float* __restrict__ norms, float* __restrict__ D) {
  __shared__ __align__(16) float Ai[67][64];
  __shared__ __align__(16) float Aj[67][64];
  const int bid = blockIdx.x;
  const int b   = bid >> 14;            // NT*NT = 16384 tiles per batch
  const int rem = bid & 16383;
  const int bi  = rem >> 7, bj = rem & (NT - 1);
  const int t   = threadIdx.x;
  const int i0  = bi * 64, j0 = bj * 64;
  const float* Pb = pts  + (size_t)b * NN * 3;
  const float* Fb = feat + (size_t)b * CC * NN;

  for (int idx = t; idx < 67 * 64; idx += 256) {
    const int c = idx >> 6, r = idx & 63;
    float vi, vj;
    if (c < 3) {
      vi = Pb[(size_t)(i0 + r) * 3 + c];
      vj = Pb[(size_t)(j0 + r) * 3 + c];
    } else {
      vi = Fb[(size_t)(c - 3) * NN + i0 + r];
      vj = Fb[(size_t)(c - 3) * NN + j0 + r];
    }
    Ai[c][r] = vi;
    Aj[c][r] = vj;
  }
  __syncthreads();

  const int tx = t & 15, ty = t >> 4;
  float acc[4][4] = {};
  for (int k = 0; k < 67; ++k) {
    const float4 a = *(const float4*)&Ai[k][ty * 4];
    const float4 v = *(const float4*)&Aj[k][tx * 4];
    acc[0][0] = fmaf(a.x, v.x, acc[0][0]); acc[0][1] = fmaf(a.x, v.y, acc[0][1]);
    acc[0][2] = fmaf(a.x, v.z, acc[0][2]); acc[0][3] = fmaf(a.x, v.w, acc[0][3]);
    acc[1][0] = fmaf(a.y, v.x, acc[1][0]); acc[1][1] = fmaf(a.y, v.y, acc[1][1]);
    acc[1][2] = fmaf(a.y, v.z, acc[1][2]); acc[1][3] = fmaf(a.y, v.w, acc[1][3]);
    acc[2][0] = fmaf(a.z, v.x, acc[2][0]); acc[2][1] = fmaf(a.z, v.y, acc[2][1]);
    acc[2][2] = fmaf(a.z, v.z, acc[2][2]); acc[2][3] = fmaf(a.z, v.w, acc[2][3]);
    acc[3][0] = fmaf(a.w, v.x, acc[3][0]); acc[3][1] = fmaf(a.w, v.y, acc[3][1]);
    acc[3][2] = fmaf(a.w, v.z, acc[3][2]); acc[3][3] = fmaf(a.w, v.w, acc[3][3]);
  }

  const float4 ni = *(const float4*)&norms[(size_t)b * NN + i0 + ty * 4];
  const float4 nj = *(const float4*)&norms[(size_t)b * NN + j0 + tx * 4];
  const float nia[4] = {ni.x, ni.y, ni.z, ni.w};
  float* Db = D + ((size_t)b << 26);
#pragma unroll
  for (int r = 0; r < 4; ++r) {
    float4 w;
    w.x = (nia[r] + nj.x) - 2.0f * acc[r][0];
    w.y = (nia[r] + nj.y) - 2.0f * acc[r][1];
    w.z = (nia[r] + nj.z) - 2.0f * acc[r][2];
    w.w = (nia[r] + nj.w) - 2.0f * acc[r][3];
    *(float4*)&Db[(size_t)(i0 + ty * 4 + r) * NN + j0 + tx * 4] = w;
  }
}

// one block per batch: serial FPS scan over precomputed rows, block-local sync only
__global__ __launch_bounds__(1024) void scan_kernel(
    const float* __restrict__ D, int* __restrict__ out) {
  const int b = blockIdx.x;
  const int tid = threadIdx.x, lane = tid & 63, wid = tid >> 6;
  __shared__ unsigned long long wred[16];
  __shared__ int far_sh;
  const float* Db = D + ((size_t)b << 26);

  float4 m0 = {3.0e38f, 3.0e38f, 3.0e38f, 3.0e38f};
  float4 m1 = m0;
  if (tid == 0) out[b * NPT] = 0;
  int far = 0;

  for (int s = 1; s < NPT; ++s) {
    const float4* row = (const float4*)(Db + (size_t)far * NN);
    const float4 v0 = row[tid];
    const float4 v1 = row[1024 + tid];
    m0.x = fminf(m0.x, v0.x); m0.y = fminf(m0.y, v0.y);
    m0.z = fminf(m0.z, v0.z); m0.w = fminf(m0.w, v0.w);
    m1.x = fminf(m1.x, v1.x); m1.y = fminf(m1.y, v1.y);
    m1.z = fminf(m1.z, v1.z); m1.w = fminf(m1.w, v1.w);

    // per-thread argmax key over its 8 elements (value desc, lowest index)
    const int ja = tid * 4, jb = 4096 + tid * 4;
    unsigned long long k, o;
    k = ((unsigned long long)fkey(m0.x) << 13) | (unsigned int)(8191 - ja);
    o = ((unsigned long long)fkey(m0.y) << 13) | (unsigned int)(8191 - (ja + 1)); k = k > o ? k : o;
    o = ((unsigned long long)fkey(m0.z) << 13) | (unsigned int)(8191 - (ja + 2)); k = k > o ? k : o;
    o = ((unsigned long long)fkey(m0.w) << 13) | (unsigned int)(8191 - (ja + 3)); k = k > o ? k : o;
    o = ((unsigned long long)fkey(m1.x) << 13) | (unsigned int)(8191 - jb);       k = k > o ? k : o;
    o = ((unsigned long long)fkey(m1.y) << 13) | (unsigned int)(8191 - (jb + 1)); k = k > o ? k : o;
    o = ((unsigned long long)fkey(m1.z) << 13) | (unsigned int)(8191 - (jb + 2)); k = k > o ? k : o;
    o = ((unsigned long long)fkey(m1.w) << 13) | (unsigned int)(8191 - (jb + 3)); k = k > o ? k : o;

#pragma unroll
    for (int off = 1; off < 64; off <<= 1) {
      o = __shfl_xor(k, off);
      k = k > o ? k : o;
    }
    if (lane == 0) wred[wid] = k;
    __syncthreads();
    if (wid == 0) {
      unsigned long long v = (lane < 16) ? wred[lane] : 0ull;
#pragma unroll
      for (int off = 8; off; off >>= 1) {
        o = __shfl_xor(v, off);
        v = v > o ? v : o;
      }
      if (lane == 0) {
        const int fr = 8191 - (int)(v & 0x1FFFu);
        far_sh = fr;
        out[b * NPT + s] = fr;
      }
    }
    __syncthreads();
    far = far_sh;
  }
}

// ======================= fallback path (small ws) =======================
// R3's register-resident compute + R2's hierarchical barrier + parity slots.

#define R64(M) \
  M(0) M(1) M(2) M(3) M(4) M(5) M(6) M(7) \
  M(8) M(9) M(10) M(11) M(12) M(13) M(14) M(15) \
  M(16) M(17) M(18) M(19) M(20) M(21) M(22) M(23) \
  M(24) M(25) M(26) M(27) M(28) M(29) M(30) M(31) \
  M(32) M(33) M(34) M(35) M(36) M(37) M(38) M(39) \
  M(40) M(41) M(42) M(43) M(44) M(45) M(46) M(47) \
  M(48) M(49) M(50) M(51) M(52) M(53) M(54) M(55) \
  M(56) M(57) M(58) M(59) M(60) M(61) M(62) M(63)

__global__ __attribute__((amdgpu_waves_per_eu(1, 2))) __launch_bounds__(TPB)
void fps_fallback(const float* __restrict__ pts, const float* __restrict__ feat,
                  int* __restrict__ out, unsigned long long* __restrict__ slots) {
  const int blk  = blockIdx.x & (NBLK - 1);
  const int b    = blockIdx.x >> 4;
  const int tid  = threadIdx.x;
  const int lane = tid & 63;
  const int p    = blk * TPB + tid;

  const float* Pp = pts  + (size_t)b * NN * 3 + (size_t)p * 3;
  const float* Fp = feat + (size_t)b * CC * NN + p;

  float fx = Pp[0], fy = Pp[1], fz = Pp[2];
#define DCF(i) float fc##i = Fp[(i) * NN];
  R64(DCF)
#undef DCF
  asm volatile("" : "+v"(fx), "+v"(fy), "+v"(fz));
#define PIN(i) asm volatile("" : "+v"(fc##i));
  R64(PIN)
#undef PIN

  float nrm = 0.f;
  nrm += fx * fx; nrm += fy * fy; nrm += fz * fz;
#define NR(i) nrm += fc##i * fc##i;
  R64(NR)
#undef NR

  __shared__ unsigned long long wred[TPB / 64];
  __shared__ int far_sh;

  if (blk == 0 && tid == 0) out[b * NPT] = 0;

  float mind = 3.0e38f;
  int far = 0;

  for (int s = 1; s < NPT; ++s) {
    const int fu = __builtin_amdgcn_readfirstlane(far);
    const float* Pq = pts  + (size_t)b * NN * 3 + (size_t)fu * 3;
    const float* Fq = feat + (size_t)b * CC * NN + fu;
    const float gx = Pq[0], gy = Pq[1], gz = Pq[2];
#define GL(i) const float gc##i = Fq[(i) * NN];
    R64(GL)
#undef GL
    float nf = 0.f, dot = 0.f;
    nf += gx * gx; nf += gy * gy; nf += gz * gz;
#define NF(i) nf += gc##i * gc##i;
    R64(NF)
#undef NF
    dot += fx * gx; dot += fy * gy; dot += fz * gz;
#define DT(i) dot += fc##i * gc##i;
    R64(DT)
#undef DT
    const float d = (nf + nrm) - 2.0f * dot;
    mind = fminf(mind, d);

    unsigned long long key =
        ((unsigned long long)fkey(mind) << 13) | (unsigned int)(8191 - p);
#pragma unroll
    for (int off = 1; off < 64; off <<= 1) {
      unsigned long long o = __shfl_xor(key, off);
      key = key > o ? key : o;
    }
    if (lane == 0) wred[tid >> 6] = key;
    __syncthreads();

    if (tid < 64) {
      unsigned long long bk = wred[0];
#pragma unroll
      for (int w = 1; w < TPB / 64; ++w) bk = bk > wred[w] ? bk : wred[w];
      unsigned long long* sb = slots + ((size_t)(s & 1) * BB + b) * NBLK;
      if (tid == 0) {
        bk |= ((unsigned long long)s << 45);
        __hip_atomic_store(&sb[blk], bk, __ATOMIC_RELEASE, __HIP_MEMORY_SCOPE_AGENT);
      }
      unsigned long long v = 0;
      for (;;) {
        if (tid < NBLK)
          v = __hip_atomic_load(&sb[tid], __ATOMIC_RELAXED, __HIP_MEMORY_SCOPE_AGENT);
        const bool ok = (tid < NBLK) ? ((v >> 45) == (unsigned long long)s) : true;
        if (__all(ok)) break;
      }
#pragma unroll
      for (int off = 8; off; off >>= 1) {
        unsigned long long o = __shfl_xor(v, off);
        v = v > o ? v : o;
      }
      if (tid == 0) far_sh = 8191 - (int)(v & 0x1FFFu);
    }
    __syncthreads();
    far = far_sh;
    if (blk == 0 && tid == 0) out[b * NPT + s] = far;
  }
}

// ======================= host =======================

extern "C" void kernel_launch(void* const* d_in, const int* in_sizes, int n_in,
                              void* d_out, int out_size, void* d_ws, size_t ws_size,
                              hipStream_t stream) {
  const float* pts  = (const float*)d_in[0];
  const float* feat = (const float*)d_in[1];
  int* out = (int*)d_out;

  const size_t needD = (((size_t)BB) << 26) * sizeof(float) + 65536; // 512 MiB + norms
  if (ws_size >= needD) {
    float* norms = (float*)d_ws;
    float* D     = (float*)((char*)d_ws + 65536);
    norm_kernel<<<BB * NN / 256, 256, 0, stream>>>(pts, feat, norms);
    dist_kernel<<<BB * NT * NT, 256, 0, stream>>>(pts, feat, norms, D);
    scan_kernel<<<BB, 1024, 0, stream>>>(D, out);
  } else {
    unsigned long long* slots = (unsigned long long*)d_ws; // [2][BB][NBLK] = 512 B
    hipMemsetAsync(d_ws, 0, 2 * BB * NBLK * sizeof(unsigned long long), stream);
    void* args[] = {(void*)&pts, (void*)&feat, (void*)&out, (void*)&slots};
    dim3 grid(BB * NBLK), block(TPB);
    hipLaunchCooperativeKernel((void*)fps_fallback, grid, block, args, 0, stream);
  }
}